// Round 4
// baseline (581.857 us; speedup 1.0000x reference)
//
#include <hip/hip_runtime.h>
#include <hip/hip_bf16.h>

typedef __bf16 bf16x8 __attribute__((ext_vector_type(8)));
typedef float  f32x4  __attribute__((ext_vector_type(4)));
typedef unsigned short u16;
typedef unsigned short u16x4 __attribute__((ext_vector_type(4)));
typedef unsigned long long u64;

#define NB 1024
#define NS 1024
#define NI 32
#define NH 128

__device__ __forceinline__ u64 pack4_bf16(f32x4 v) {
  u16x4 p;
#pragma unroll
  for (int r = 0; r < 4; ++r) p[r] = __builtin_bit_cast(u16, (__bf16)v[r]);
  return __builtin_bit_cast(u64, p);
}

// Barrier that drains lgkmcnt only (no vmcnt): global stores/loads stay in flight.
__device__ __forceinline__ void lds_barrier() {
  __builtin_amdgcn_sched_barrier(0);
  asm volatile("s_waitcnt lgkmcnt(0)" ::: "memory");
  __builtin_amdgcn_s_barrier();
  asm volatile("" ::: "memory");
  __builtin_amdgcn_sched_barrier(0);
}

// Block: 512 threads = 8 waves (2/SIMD). Block owns 16 batch rows for the whole scan.
// Wave w computes hidden cols [16w, 16w+16).
// MFMA: D'[n][m] = sum_k U[k][n] * h[m][k]  (A' = U^T slice, B' = h^T)
//   B'-frag: lane l holds h[m=l&15][k = 32kt + 8(l>>4) + j]   (one ds_read_b128)
//   D'     : lane l holds h_new[m=l&15][n = 16w + 4(l>>4) + r]
// h ping-pongs in LDS as bf16 (u64 units swizzled by unit ^ ((row&7)<<1)).
// x fragments are loaded per-wave directly from global (L1-shared), 2 steps ahead.
__global__ __launch_bounds__(512, 2) void gru_scan(
    const float* __restrict__ x,
    const float* __restrict__ Wz, const float* __restrict__ Uz, const float* __restrict__ bz,
    const float* __restrict__ Wh, const float* __restrict__ Uh, const float* __restrict__ bh,
    float* __restrict__ out)
{
  __shared__ __align__(16) u64 hbuf[2][16][32];   // 8 KB

  const int tid  = threadIdx.x;
  const int lane = tid & 63;
  const int w    = tid >> 6;     // wave 0..7
  const int ml   = lane & 15;    // batch row in tile
  const int g    = lane >> 4;    // k-group / reg-group
  const int rb   = blockIdx.x * 16;

  // ---- persistent weight fragments ----
  bf16x8 ufrag[2][4];   // [gate][kt]
  bf16x8 wfrag[2];      // [gate]
  f32x4  bias2[2];      // [gate], D layout
  {
    const float* Ug[2] = {Uz, Uh};
    const float* Wg[2] = {Wz, Wh};
    const float* bg[2] = {bz, bh};
    const int n0 = 16 * w + ml;   // A'-row = hidden col
#pragma unroll
    for (int gate = 0; gate < 2; ++gate) {
#pragma unroll
      for (int kt = 0; kt < 4; ++kt)
#pragma unroll
        for (int j = 0; j < 8; ++j)
          ufrag[gate][kt][j] = (__bf16)Ug[gate][(32 * kt + 8 * g + j) * NH + n0];
#pragma unroll
      for (int j = 0; j < 8; ++j)
        wfrag[gate][j] = (__bf16)Wg[gate][(8 * g + j) * NH + n0];
      const int nb = 16 * w + 4 * g;
#pragma unroll
      for (int r = 0; r < 4; ++r) bias2[gate][r] = bg[gate][nb + r];
    }
  }

  // h0 = 0
  for (int i = tid; i < 16 * 32; i += 512) hbuf[0][i >> 5][i & 31] = 0ULL;

  // per-lane LDS constants
  const int sw = (ml & 7) << 1;
  int ridx[4];
#pragma unroll
  for (int kt = 0; kt < 4; ++kt) ridx[kt] = (8 * kt + 2 * g) ^ sw;  // even -> b128 ok
  const int widx = (4 * w + g) ^ sw;

  const float NL2E  = -1.4426950408889634f;  // -log2(e)
  const float P2L2E =  2.8853900817779268f;  //  2*log2(e)
  const f32x4 zero4 = {0.f, 0.f, 0.f, 0.f};

  // ---- x direct-global prefetch (per-wave fragment rows) ----
  // lane reads x[rb+ml][t][8g .. 8g+7]
  const float* xrow = x + (size_t)(rb + ml) * (NS * NI) + 8 * g;

  f32x4 xv0a, xv0b, xv1a, xv1b;   // parity-indexed x prefetch regs
  f32x4 ax0z, ax0h, ax1z, ax1h;   // parity-indexed ax = bias + x_t @ W

  {
    // x(0) -> ax0 ; x(1) -> buf[1]
    f32x4 t0a = ((const f32x4*)xrow)[0];
    f32x4 t0b = ((const f32x4*)xrow)[1];
    xv1a = ((const f32x4*)(xrow + NI))[0];
    xv1b = ((const f32x4*)(xrow + NI))[1];
    bf16x8 xf;
#pragma unroll
    for (int j = 0; j < 4; ++j) { xf[j] = (__bf16)t0a[j]; xf[4 + j] = (__bf16)t0b[j]; }
    ax0z = __builtin_amdgcn_mfma_f32_16x16x32_bf16(wfrag[0], xf, bias2[0], 0, 0, 0);
    ax0h = __builtin_amdgcn_mfma_f32_16x16x32_bf16(wfrag[1], xf, bias2[1], 0, 0, 0);
  }

  f32x4 hv = {0.f, 0.f, 0.f, 0.f};
  float* optr = out + (size_t)(rb + ml) * NS * NH + 16 * w + 4 * g;

  __syncthreads();   // hbuf[0] visible; cold full drain is fine here

  // Step body. P = t&1 (compile-time). Consumes ax{P}, produces ax{P^1} (for t+1).
  // x regs: cvt buf[P^1] (holds x(t+1)); load x(t+2) into buf[P].
#define GRU_STEP(P, T, AXZ_C, AXH_C, AXZ_N, AXH_N, XVA_C, XVB_C, XVA_N, XVB_N, DO_STORE)   \
  {                                                                                        \
    /* 1. h fragment reads (post-barrier; everything below fills their shadow) */          \
    const u64* hrow = &hbuf[P][ml][0];                                                     \
    bf16x8 hf0 = *(const bf16x8*)(hrow + ridx[0]);                                         \
    bf16x8 hf1 = *(const bf16x8*)(hrow + ridx[1]);                                         \
    bf16x8 hf2 = *(const bf16x8*)(hrow + ridx[2]);                                         \
    bf16x8 hf3 = *(const bf16x8*)(hrow + ridx[3]);                                         \
    /* 2. issue x loads for t+2 into buf[P] */                                             \
    {                                                                                      \
      int tf = (T) + 2; if (tf > NS - 1) tf = NS - 1;                                      \
      const f32x4* xp = (const f32x4*)(xrow + (size_t)tf * NI);                            \
      XVA_N = xp[0]; XVB_N = xp[1];                                                        \
    }                                                                                      \
    /* 3. cvt x(t+1) (buf[P^1], arrived >=1 step ago) + ax(t+1) MFMAs */                   \
    {                                                                                      \
      bf16x8 xf;                                                                           \
      _Pragma("unroll")                                                                    \
      for (int j = 0; j < 4; ++j) { xf[j] = (__bf16)XVA_C[j]; xf[4+j] = (__bf16)XVB_C[j]; }\
      AXZ_N = __builtin_amdgcn_mfma_f32_16x16x32_bf16(wfrag[0], xf, bias2[0], 0, 0, 0);    \
      AXH_N = __builtin_amdgcn_mfma_f32_16x16x32_bf16(wfrag[1], xf, bias2[1], 0, 0, 0);    \
    }                                                                                      \
    /* 4. stream previous step's output (fills read shadow; no vmcnt wait) */              \
    if (DO_STORE) { __builtin_nontemporal_store(hv, (f32x4*)optr); optr += NH; }           \
    /* 5. h-dependent MFMAs: 4 independent chains of 2 */                                  \
    f32x4 z1 = __builtin_amdgcn_mfma_f32_16x16x32_bf16(ufrag[0][0], hf0, AXZ_C, 0, 0, 0);  \
    f32x4 h1 = __builtin_amdgcn_mfma_f32_16x16x32_bf16(ufrag[1][0], hf0, AXH_C, 0, 0, 0);  \
    f32x4 z2 = __builtin_amdgcn_mfma_f32_16x16x32_bf16(ufrag[0][2], hf2, zero4, 0, 0, 0);  \
    f32x4 h2 = __builtin_amdgcn_mfma_f32_16x16x32_bf16(ufrag[1][2], hf2, zero4, 0, 0, 0);  \
    z1 = __builtin_amdgcn_mfma_f32_16x16x32_bf16(ufrag[0][1], hf1, z1, 0, 0, 0);           \
    h1 = __builtin_amdgcn_mfma_f32_16x16x32_bf16(ufrag[1][1], hf1, h1, 0, 0, 0);           \
    z2 = __builtin_amdgcn_mfma_f32_16x16x32_bf16(ufrag[0][3], hf3, z2, 0, 0, 0);           \
    h2 = __builtin_amdgcn_mfma_f32_16x16x32_bf16(ufrag[1][3], hf3, h2, 0, 0, 0);           \
    const f32x4 az = z1 + z2;                                                              \
    const f32x4 ah = h1 + h2;                                                              \
    /* 6. z = sigmoid(az); hh = tanh(ah); h += z*(hh-h) */                                 \
    f32x4 hn;                                                                              \
    _Pragma("unroll")                                                                      \
    for (int r = 0; r < 4; ++r) {                                                          \
      float ez = __builtin_amdgcn_exp2f(az[r] * NL2E);                                     \
      float zz = __builtin_amdgcn_rcpf(1.f + ez);                                          \
      float eh = __builtin_amdgcn_exp2f(ah[r] * P2L2E);                                    \
      float th = 1.f - 2.f * __builtin_amdgcn_rcpf(1.f + eh);                              \
      hn[r] = __builtin_fmaf(zz, th - hv[r], hv[r]);                                       \
    }                                                                                      \
    hv = hn;                                                                               \
    /* 7. publish bf16 h(t+1); short pre-barrier tail */                                   \
    hbuf[P ^ 1][ml][widx] = pack4_bf16(hn);                                                \
    lds_barrier();                                                                         \
  }

  for (int tp = 0; tp < NS / 2; ++tp) {
    const int tbase = 2 * tp;
    GRU_STEP(0, tbase,     ax0z, ax0h, ax1z, ax1h, xv1a, xv1b, xv0a, xv0b, (tp > 0))
    GRU_STEP(1, tbase + 1, ax1z, ax1h, ax0z, ax0h, xv0a, xv0b, xv1a, xv1b, true)
  }

  // final output element + h_last
  __builtin_nontemporal_store(hv, (f32x4*)optr);   // out[.., NS-1, ..]
  const size_t lbase = (size_t)NB * NS * NH + (size_t)(rb + ml) * NH + 16 * w + 4 * g;
  *(f32x4*)(out + lbase) = hv;
}

extern "C" void kernel_launch(void* const* d_in, const int* in_sizes, int n_in,
                              void* d_out, int out_size, void* d_ws, size_t ws_size,
                              hipStream_t stream) {
  const float* x  = (const float*)d_in[0];
  // d_in[1..3] = W_r, U_r, b_r: unused (r gate never affects the output)
  const float* Wz = (const float*)d_in[4];
  const float* Uz = (const float*)d_in[5];
  const float* bz = (const float*)d_in[6];
  const float* Wh = (const float*)d_in[7];
  const float* Uh = (const float*)d_in[8];
  const float* bh = (const float*)d_in[9];
  float* out = (float*)d_out;

  gru_scan<<<dim3(NB / 16), dim3(512), 0, stream>>>(x, Wz, Uz, bz, Wh, Uh, bh, out);
}